// Round 13
// baseline (236.042 us; speedup 1.0000x reference)
//
#include <hip/hip_runtime.h>

// ---------------------------------------------------------------------------
// SAGE 3-layer GNN.  (R20 = R19 + 16-row GEMM tiles: 625 blocks, 4/CU LDS,
//                     1-row/thread chains, no split-K combine)
//   Per layer: S = X@W_self + b (fp32) ; P = X@W_neigh (bf16 row-major)
//              h[i] = act( S[i] + (sum_{j in N_in(i)} P[j]) / max(deg_i,1) )
//
// Evidence log:
//   R0..R5: random row-gather agg ~150us = per-CU gather service wall.
//   R9 WIN: src-bucket LDS slicing. R10 WIN: sorted-graph_id finish.
//   R11 WIN: one-pass fixed-cap CSR build. 255.9us.
//   R12/R13/R14: persistent-kernel route FAILED. Reverted.
//   R15 WIN (249.1): build fused into gemm1; readout ticket-fused.
//   R16 WIN (232.5): split-K wave-group GEMMs.
//   R17/R18 (net ~flat): atomic-free agg planes + branchless consumer sum.
//   R19 NEUTRAL (234.9): vectorized LDS reads — instr count wasn't the wall.
//   R20 (this round): all GEMM dispatches had grid=157 blocks on 256 CUs
//     (40% idle) + long per-thread K-chains. Re-tile to 16 rows x 64 cols,
//     256 thr, 1 row x 4 cols/thread: per kk = 1 broadcast A-read +
//     2 ds_read_b128 + 8 FMA; acc = 8 VGPR; LDS 38KB -> 4 blocks/CU;
//     grid 625 (= M/16 exactly) covers every CU ~2.4x. Split-K combine
//     deleted. Build rides in gemm1 dispatch (256-thr blocks).
//     Agg/finish unchanged (single variable).
//   Predicted: gemm1_build ~28 -> 15-20, gemm2/3 ~10 -> 5-7 each,
//     total 234.9 -> ~215-225. If <5us move -> gaps/fill dominate ->
//     flag-chaining or converged.
// ---------------------------------------------------------------------------

#define DH 64
#define NG 16
#define NSB 8        // src buckets
#define DTILES 32    // dst tiles -> grid 8*32 = 256 agg blocks (1/CU)
#define MAXNPB 1250  // max nodes per bucket (M <= 10000)
#define CAP 32       // edge slots per (dst,bucket) row; Poisson(4) tail ~1e-19
#define GROWS 16     // gemm tile rows
#define XS_F  1088   // 16*68 floats
#define W_F   4352   // 64*68 floats

__device__ __forceinline__ unsigned short f2bf(float f) {
    unsigned int u = __float_as_uint(f);
    unsigned int r = (u + 0x7FFFu + ((u >> 16) & 1u)) >> 16;   // RNE
    return (unsigned short)r;
}
__device__ __forceinline__ float bfu(unsigned short v) {
    return __uint_as_float(((unsigned int)v) << 16);
}

// ---- shared gemm tile body (16 rows x 64 cols, 256 threads) ---------------
// thread t: row = t>>4 (1 row), cols 4*(t&15)..+3. Per kk: 1 b32 A-broadcast
// + 2 ds_read_b128 B + 8 FMA. FUSE: X-row = relu(S + sum(planes)/deg).
template <int K, bool FUSE>
__device__ __forceinline__ void gemm_tile16(
    const float* __restrict__ X, const float* __restrict__ Ws_g,
    const float* __restrict__ Wn_g, const float* __restrict__ bias,
    const float* __restrict__ Hn_part, const int* __restrict__ cnt8,
    float* __restrict__ S, unsigned short* __restrict__ P,
    int M, int tile, float* smem) {
    float* Xs  = smem;                 // [16][68]
    float* Wsm = smem + XS_F;          // [64][68]
    float* Wnm = Wsm + W_F;            // [64][68]
    const int t   = threadIdx.x;
    const int cx  = t & 15;            // col base 4*cx
    const int row = t >> 4;            // 0..15
    const int row0 = tile * GROWS;
    float4 acc_s = make_float4(0.f, 0.f, 0.f, 0.f);
    float4 acc_n = make_float4(0.f, 0.f, 0.f, 0.f);

    for (int kc = 0; kc < K; kc += 64) {
        {   // stage Xs: 1 float4/thread (rows 0..15 x k4 0..15)
            int k4 = cx * 4;
            int gr = row0 + row;
            float4 xv = make_float4(0.f, 0.f, 0.f, 0.f);
            if (gr < M) {
                xv = *reinterpret_cast<const float4*>(&X[(size_t)gr * K + kc + k4]);
                if constexpr (FUSE) {   // K==64, kc==0
                    const int4* cp = reinterpret_cast<const int4*>(&cnt8[gr * NSB]);
                    int4 c0 = cp[0], c1 = cp[1];
                    int ca[8] = {c0.x, c0.y, c0.z, c0.w, c1.x, c1.y, c1.z, c1.w};
                    int deg = ca[0] + ca[1] + ca[2] + ca[3] +
                              ca[4] + ca[5] + ca[6] + ca[7];
                    float4 pv[8];
                    size_t pb = (size_t)gr * NSB * DH + k4;
#pragma unroll
                    for (int b = 0; b < NSB; ++b)
                        pv[b] = *reinterpret_cast<const float4*>(&Hn_part[pb + b * DH]);
                    float4 hv = make_float4(0.f, 0.f, 0.f, 0.f);
#pragma unroll
                    for (int b = 0; b < NSB; ++b) {
                        bool use = ca[b] > 0;
                        hv.x += use ? pv[b].x : 0.f;
                        hv.y += use ? pv[b].y : 0.f;
                        hv.z += use ? pv[b].z : 0.f;
                        hv.w += use ? pv[b].w : 0.f;
                    }
                    float inv = 1.f / fmaxf((float)deg, 1.f);
                    xv.x = fmaxf(fmaf(hv.x, inv, xv.x), 0.f);
                    xv.y = fmaxf(fmaf(hv.y, inv, xv.y), 0.f);
                    xv.z = fmaxf(fmaf(hv.z, inv, xv.z), 0.f);
                    xv.w = fmaxf(fmaf(hv.w, inv, xv.w), 0.f);
                }
            }
            *reinterpret_cast<float4*>(&Xs[row * 68 + k4]) = xv;
        }
        // stage Ws/Wn: 4 float4 each per thread (64 rows x 16 k4-groups)
#pragma unroll
        for (int it = 0; it < 4; ++it) {
            int q = t + 256 * it;      // 0..1023
            int wr = q >> 4;
            int k4 = (q & 15) * 4;
            *reinterpret_cast<float4*>(&Wsm[wr * 68 + k4]) =
                *reinterpret_cast<const float4*>(&Ws_g[(size_t)(kc + wr) * 64 + k4]);
            *reinterpret_cast<float4*>(&Wnm[wr * 68 + k4]) =
                *reinterpret_cast<const float4*>(&Wn_g[(size_t)(kc + wr) * 64 + k4]);
        }
        __syncthreads();
#pragma unroll 8
        for (int kk = 0; kk < 64; ++kk) {
            float a = Xs[row * 68 + kk];
            float4 bs4 = *reinterpret_cast<const float4*>(&Wsm[kk * 68 + cx * 4]);
            float4 bn4 = *reinterpret_cast<const float4*>(&Wnm[kk * 68 + cx * 4]);
            acc_s.x += a * bs4.x; acc_s.y += a * bs4.y;
            acc_s.z += a * bs4.z; acc_s.w += a * bs4.w;
            acc_n.x += a * bn4.x; acc_n.y += a * bn4.y;
            acc_n.z += a * bn4.z; acc_n.w += a * bn4.w;
        }
        __syncthreads();
    }

    int r = row0 + row;
    if (r < M) {
        int col = cx * 4;
        float4 b4 = *reinterpret_cast<const float4*>(&bias[col]);
        float4 sv;
        sv.x = acc_s.x + b4.x; sv.y = acc_s.y + b4.y;
        sv.z = acc_s.z + b4.z; sv.w = acc_s.w + b4.w;
        *reinterpret_cast<float4*>(&S[(size_t)r * DH + col]) = sv;
        ushort4 pk;
        pk.x = f2bf(acc_n.x); pk.y = f2bf(acc_n.y);
        pk.z = f2bf(acc_n.z); pk.w = f2bf(acc_n.w);
        *reinterpret_cast<ushort4*>(&P[(size_t)r * DH + col]) = pk;
    }
}

// ---- fused: layer-1 gemm tiles (blocks [0,gb)) + CSR build ([gb,gb+eb)) ---
__global__ __launch_bounds__(256) void gemm1_build_kernel(
    const float* __restrict__ X, const float* __restrict__ Ws_g,
    const float* __restrict__ Wn_g, const float* __restrict__ bias,
    float* __restrict__ S, unsigned short* __restrict__ P,
    const int* __restrict__ src, const int* __restrict__ dst,
    int* __restrict__ cnt8, unsigned short* __restrict__ es16,
    int M, int E, int npb8, int gb) {
    if ((int)blockIdx.x >= gb) {          // ---- build part ----
        int i = ((int)blockIdx.x - gb) * 256 + threadIdx.x;
        if (i < E) {
            int s = src[i];
            int b = s / npb8;
            int k = dst[i] * NSB + b;
            int p = atomicAdd(&cnt8[k], 1);
            if (p < CAP)                   // clamp: memory-safe
                es16[(size_t)k * CAP + p] = (unsigned short)(s - b * npb8);
        }
        return;
    }
    __shared__ float smem[XS_F + 2 * W_F];   // 38 KB
    gemm_tile16<256, false>(X, Ws_g, Wn_g, bias, nullptr, nullptr,
                            S, P, M, blockIdx.x, smem);
}

// ---- gemm layers 2/3 (K=64, FUSE loader) ----------------------------------
__global__ __launch_bounds__(256) void gemm_dual_kernel(
    const float* __restrict__ X, const float* __restrict__ Ws_g,
    const float* __restrict__ Wn_g, const float* __restrict__ bias,
    const float* __restrict__ Hn_part, const int* __restrict__ cnt8,
    float* __restrict__ S, unsigned short* __restrict__ P, int M) {
    __shared__ float smem[XS_F + 2 * W_F];   // 38 KB
    gemm_tile16<64, true>(X, Ws_g, Wn_g, bias, Hn_part, cnt8,
                          S, P, M, blockIdx.x, smem);
}

// ---- aggregation: src-bucket LDS slice, wave-per-(dst,bucket) row ----------
// grid = NSB * DTILES blocks x 1024 threads. LDS = 1250*64 bf16 = 160,000 B.
// ATOMIC-FREE: one writer per row -> plain coalesced 256B partial-plane store.
__global__ __launch_bounds__(1024) void agg_kernel(
    const unsigned short* __restrict__ P, const int* __restrict__ cnt8,
    const unsigned short* __restrict__ es16, float* __restrict__ Hn_part,
    int M, int npb8) {
    __shared__ __align__(16) unsigned short sP[MAXNPB * DH];
    int tid = threadIdx.x;
    int sb    = blockIdx.x & (NSB - 1);
    int dtile = blockIdx.x >> 3;
    int s0 = sb * npb8;
    int snodes = min(npb8, M - s0);

    // stage this bucket's P slice (coalesced uint4)
    {
        const uint4* gp = reinterpret_cast<const uint4*>(P + (size_t)s0 * DH);
        int cnt = snodes * 8;   // 128 B/node / 16 B
        for (int j = tid; j < cnt; j += 1024)
            *reinterpret_cast<uint4*>(&sP[j * 8]) = gp[j];
    }
    __syncthreads();

    int lane = tid & 63, wid = tid >> 6;
    int dpb  = (M + DTILES - 1) / DTILES;
    int d0t  = dtile * dpb;
    int dend = min(d0t + dpb, M);

    for (int dstn = d0t + wid; dstn < dend; dstn += 16) {
        int key = dstn * NSB + sb;
        int cnt = min(cnt8[key], CAP);
        if (cnt == 0) continue;
        size_t base = (size_t)key * CAP;
        float acc = 0.f;
        int cmax = cnt - 1;
        for (int e = 0; e < cnt; e += 4) {
            int i0 = es16[base + min(e + 0, cmax)];
            int i1 = es16[base + min(e + 1, cmax)];
            int i2 = es16[base + min(e + 2, cmax)];
            int i3 = es16[base + min(e + 3, cmax)];
            float m1 = (e + 1 < cnt) ? 1.f : 0.f;
            float m2 = (e + 2 < cnt) ? 1.f : 0.f;
            float m3 = (e + 3 < cnt) ? 1.f : 0.f;
            float f0 = bfu(sP[(size_t)i0 * DH + lane]);
            float f1 = bfu(sP[(size_t)i1 * DH + lane]);
            float f2 = bfu(sP[(size_t)i2 * DH + lane]);
            float f3 = bfu(sP[(size_t)i3 * DH + lane]);
            acc += f0;                       // e+0 always valid in-loop
            acc = fmaf(m1, f1, acc);
            acc = fmaf(m2, f2, acc);
            acc = fmaf(m3, f3, acc);
        }
        Hn_part[(size_t)key * DH + lane] = acc;   // plain coalesced 256 B
    }
}

// ---- fused finish + readout (last-block-done ticket) ----------------------
// finish: H = S + sum(partials)/deg (no relu) + per-graph register
// accumulation (graph_id sorted). Branchless 8-plane sum; fb=320.
__global__ __launch_bounds__(256) void finish_readout_kernel(
    const float* __restrict__ S, const float* __restrict__ Hn_part,
    const int* __restrict__ cnt8, const int* __restrict__ graph_id,
    float* __restrict__ H, float* __restrict__ gsum, float* __restrict__ gcnt,
    const float* __restrict__ Wc, const float* __restrict__ bc,
    float* __restrict__ out, float* __restrict__ out_feat,
    unsigned int* __restrict__ done, int M, int fb) {
    int tid  = threadIdx.x;
    int lane = tid & 63;
    int wv   = tid >> 6;
    {   // ---- finish work ----
        int wid = blockIdx.x * 4 + wv;
        int nw  = fb * 4;
        int cpw = (M + nw - 1) / nw;
        int n0 = wid * cpw, n1 = min(n0 + cpw, M);
        if (n0 < n1) {
            float acc = 0.f;
            int cnt = 0;
            int cur = graph_id[n0];
            for (int n = n0; n < n1; ++n) {
                int gid = graph_id[n];
                if (gid != cur) {
                    atomicAdd(&gsum[cur * DH + lane], acc);
                    if (lane == 0) atomicAdd(&gcnt[cur], (float)cnt);
                    acc = 0.f; cnt = 0; cur = gid;
                }
                const int4* cp = reinterpret_cast<const int4*>(&cnt8[n * NSB]);
                int4 c0 = cp[0], c1 = cp[1];
                int ca[8] = {c0.x, c0.y, c0.z, c0.w, c1.x, c1.y, c1.z, c1.w};
                int deg = ca[0] + ca[1] + ca[2] + ca[3] +
                          ca[4] + ca[5] + ca[6] + ca[7];
                // branchless: 8 unconditional parallel loads, then select
                float pv[8];
                size_t pb = (size_t)n * NSB * DH + lane;
#pragma unroll
                for (int b = 0; b < NSB; ++b) pv[b] = Hn_part[pb + b * DH];
                float hn = 0.f;
#pragma unroll
                for (int b = 0; b < NSB; ++b) hn += (ca[b] > 0) ? pv[b] : 0.f;
                float inv = 1.f / fmaxf((float)deg, 1.f);
                size_t o = (size_t)n * DH + lane;
                float val = fmaf(hn, inv, S[o]);
                H[o] = val;
                acc += val;
                ++cnt;
            }
            atomicAdd(&gsum[cur * DH + lane], acc);
            if (lane == 0) atomicAdd(&gcnt[cur], (float)cnt);
        }
    }

    // ---- last-block ticket ----
    __shared__ unsigned int s_ticket;
    __syncthreads();
    if (tid == 0) {
        __threadfence();   // release: publish this block's gsum/gcnt/H
        s_ticket = __hip_atomic_fetch_add(done, 1u, __ATOMIC_ACQ_REL,
                                          __HIP_MEMORY_SCOPE_AGENT);
    }
    __syncthreads();
    if (s_ticket != (unsigned int)(fb - 1)) return;
    if (tid == 0) __threadfence();   // acquire: see all blocks' gsum/gcnt
    __syncthreads();

    // ---- readout by the last block (256 threads, 4 entries each) ----
    __shared__ float ofs[NG][DH];
#pragma unroll
    for (int q = 0; q < 4; ++q) {
        int idx = tid + 256 * q;            // 0..1023 = (g,d)
        int g = idx >> 6, d = idx & 63;
        float of = gsum[idx] / fmaxf(gcnt[g], 1.0f);
        out_feat[idx] = of;
        ofs[g][d] = of;
    }
    __syncthreads();
    if (tid < NG * 2) {
        int gg = tid >> 1, cc = tid & 1;
        float accv = bc[cc];
#pragma unroll 8
        for (int dd = 0; dd < DH; ++dd) accv += ofs[gg][dd] * Wc[dd * 2 + cc];
        out[gg * 2 + cc] = accv;
    }
}

extern "C" void kernel_launch(void* const* d_in, const int* in_sizes, int n_in,
                              void* d_out, int out_size, void* d_ws, size_t ws_size,
                              hipStream_t stream) {
    const float* feat     = (const float*)d_in[0];
    const int*   src      = (const int*)d_in[1];
    const int*   dst      = (const int*)d_in[2];
    const int*   graph_id = (const int*)d_in[3];
    const float* Ws1 = (const float*)d_in[4];
    const float* Wn1 = (const float*)d_in[5];
    const float* b1  = (const float*)d_in[6];
    const float* Ws2 = (const float*)d_in[7];
    const float* Wn2 = (const float*)d_in[8];
    const float* b2  = (const float*)d_in[9];
    const float* Ws3 = (const float*)d_in[10];
    const float* Wn3 = (const float*)d_in[11];
    const float* b3  = (const float*)d_in[12];
    const float* Wc  = (const float*)d_in[13];
    const float* bc  = (const float*)d_in[14];

    const int M  = in_sizes[3];     // 10000 nodes
    const int E  = in_sizes[1];     // 320000 edges
    const int M2 = M * NSB;         // 80000 (dst,bucket) rows
    const int npb8 = (M + NSB - 1) / NSB;   // 1250 (<= MAXNPB)

    float* out      = (float*)d_out;             // 16 x 2
    float* out_feat = out + NG * 2;              // 16 x 64
    float* Hbuf     = out_feat + NG * DH;        // 10000 x 64 (final h)

    // workspace layout (256B-aligned carves)
    char* w = (char*)d_ws;
    size_t off = 0;
    auto carve = [&](size_t bytes) {
        size_t o = off;
        off = (off + bytes + 255) & ~(size_t)255;
        return o;
    };
    int*   cnt8  = (int*)  (w + carve((size_t)M2 * 4));
    float* gsum  = (float*)(w + carve((size_t)NG * DH * 4));
    float* gcnt  = (float*)(w + carve((size_t)NG * 4));
    unsigned int* done = (unsigned int*)(w + carve(4));
    size_t zero_bytes = off;                       // cnt8 + gsum + gcnt + done
    unsigned short* es16 = (unsigned short*)(w + carve((size_t)M2 * CAP * 2)); // 5.12 MB
    float* Sbuf  = (float*)(w + carve((size_t)M * DH * 4));
    unsigned short* Pbuf = (unsigned short*)(w + carve((size_t)M * DH * 2));
    float* Hn_part = (float*)(w + carve((size_t)M2 * DH * 4));   // 20.48 MB
    (void)ws_size; (void)n_in; (void)out_size;

    (void)hipMemsetAsync(d_ws, 0, zero_bytes, stream);

    int gb = (M + GROWS - 1) / GROWS;   // 625 gemm tiles
    int eb = (E + 255) / 256;           // 1250 build blocks (256 thr)
    int ab = NSB * DTILES;              // 256 agg blocks (1/CU)
    int fb = 320;                       // finish blocks: 1280 waves

    // layer 1 (K=256, 16-row tiles) + CSR build, ONE dispatch
    gemm1_build_kernel<<<gb + eb, 256, 0, stream>>>(
        feat, Ws1, Wn1, b1, Sbuf, Pbuf,
        src, dst, cnt8, es16, M, E, npb8, gb);
    agg_kernel<<<ab, 1024, 0, stream>>>(Pbuf, cnt8, es16, Hn_part, M, npb8);

    // layer 2 (K=64): X = relu(S1 + sum(partials)/deg) fused;
    // in-place S is block-safe (block reads its 16 rows before writing them)
    gemm_dual_kernel<<<gb, 256, 0, stream>>>(
        Sbuf, Ws2, Wn2, b2, Hn_part, cnt8, Sbuf, Pbuf, M);
    agg_kernel<<<ab, 1024, 0, stream>>>(Pbuf, cnt8, es16, Hn_part, M, npb8);

    // layer 3 (K=64): X = relu(S2 + sum(partials)/deg) fused
    gemm_dual_kernel<<<gb, 256, 0, stream>>>(
        Sbuf, Ws3, Wn3, b3, Hn_part, cnt8, Sbuf, Pbuf, M);
    agg_kernel<<<ab, 1024, 0, stream>>>(Pbuf, cnt8, es16, Hn_part, M, npb8);

    // finish layer 3 + readout (fused via last-block-done ticket)
    finish_readout_kernel<<<fb, 256, 0, stream>>>(
        Sbuf, Hn_part, cnt8, graph_id, Hbuf, gsum, gcnt,
        Wc, bc, out, out_feat, done, M, fb);
}

// Round 14
// 234.198 us; speedup vs baseline: 1.0079x; 1.0079x over previous
//
#include <hip/hip_runtime.h>

// ---------------------------------------------------------------------------
// SAGE 3-layer GNN.  (R21 = exact revert to R16, the session's best: 232.5us)
//   Per layer: S = X@W_self + b (fp32) ; P = X@W_neigh (bf16 row-major)
//              h[i] = act( S[i] + (sum_{j in N_in(i)} P[j]) / max(deg_i,1) )
//
// Evidence log:
//   R0..R5: random row-gather agg ~150us = per-CU gather service wall.
//   R8 FAILED: dim-sliced LDS planes (32x edge visits).
//   R9 WIN: src-bucket LDS slicing + coalesced 256B Hn atomics.
//   R10 WIN: finish via sorted-graph_id register accumulation.
//   R11 WIN: one-pass fixed-cap CSR build. 255.9us.
//   R12/R13/R14: persistent-kernel route FAILED (capture kill; L2-inval spin
//     storm; structurally higher coherence-traffic floor: 441us best).
//   R15 WIN (249.1): build fused into gemm1 dispatch; readout ticket-fused
//     into finish.
//   R16 WIN (232.5): split-K wave-group GEMMs (2 waves/SIMD). BEST.
//   R17 FAILED (259.0): atomic-free agg planes -> consumer serial-chain blew
//     up finish (53.8us). R18 repair (236.8): branchless sum + 4x waves —
//     net ~flat vs R16. R19 vector-LDS (234.9) neutral. R20 16-row tiles
//     (236.0) neutral. GEMM-shape arc exhausted; plane arc never beat R16.
//   R21: revert to R16 byte-identical. Remaining budget = harness fill tax
//     (~43us, inside dur_us, immovable) + 7 inherently-sequential dependent
//     dispatches (each too small to fill 256 CUs) + launch gaps. The only
//     merge mechanism (device grid sync) measured WORSE (R13/R14).
//   Predicted: ~230-236us (reproduce R16). If confirmed -> declare
//     convergence next round.
// ---------------------------------------------------------------------------

#define DH 64
#define NG 16
#define NSB 8        // src buckets
#define DTILES 32    // dst tiles -> grid 8*32 = 256 agg blocks (1/CU)
#define MAXNPB 1250  // max nodes per bucket (M <= 10000)
#define CAP 32       // edge slots per (dst,bucket) row; Poisson(4) tail ~1e-19
#define TILE_F 4352  // 64*68 floats per LDS tile

__device__ __forceinline__ unsigned short f2bf(float f) {
    unsigned int u = __float_as_uint(f);
    unsigned int r = (u + 0x7FFFu + ((u >> 16) & 1u)) >> 16;   // RNE
    return (unsigned short)r;
}
__device__ __forceinline__ float bfu(unsigned short v) {
    return __uint_as_float(((unsigned int)v) << 16);
}
__device__ __forceinline__ int deg8(const int* __restrict__ cnt8, int n) {
    const int4* cp = reinterpret_cast<const int4*>(&cnt8[n * NSB]);
    int4 c0 = cp[0], c1 = cp[1];
    return c0.x + c0.y + c0.z + c0.w + c1.x + c1.y + c1.z + c1.w;
}

// ---- fused: layer-1 dual GEMM (blocks [0,gb)) + CSR build ([gb,gb+eb)) ----
// gemm: split-K wave groups — grp0 kc{0,64}, grp1 kc{128,192}, private LDS;
// grp1 dumps fp32 partials to its (dead) LDS region stride-33 (bank-free);
// grp0 adds + epilogue (S, P, Hn=0).
// build: one edge per thread, p=atomicAdd(cnt8[key]); es[key*CAP+p]=src.
__global__ __launch_bounds__(512) void gemm1_build_kernel(
    const float* __restrict__ X, const float* __restrict__ Ws_g,
    const float* __restrict__ Wn_g, const float* __restrict__ bias,
    float* __restrict__ S, unsigned short* __restrict__ P,
    float* __restrict__ Hn_out,
    const int* __restrict__ src, const int* __restrict__ dst,
    int* __restrict__ cnt8, int* __restrict__ es,
    int M, int E, int npb8, int gb) {
    constexpr int K = 256;
    int tid = threadIdx.x;

    if ((int)blockIdx.x >= gb) {          // ---- build part ----
        int i = ((int)blockIdx.x - gb) * 512 + tid;
        if (i < E) {
            int s = src[i];
            int k = dst[i] * NSB + s / npb8;
            int p = atomicAdd(&cnt8[k], 1);
            if (p < CAP) es[(size_t)k * CAP + p] = s;   // clamp: memory-safe
        }
        return;
    }

    // ---- gemm part: split-K over 2 wave groups ----
    __shared__ float smem[6 * TILE_F];    // grp0: Xs,Ws,Wn ; grp1: Xs,Ws,Wn
    const int grp = tid >> 8;             // 0: waves 0-3, 1: waves 4-7
    const int t   = tid & 255;
    const int cx = t & 15;
    const int ry = t >> 4;
    float* Xs  = smem + grp * 3 * TILE_F;
    float* Wsm = Xs + TILE_F;
    float* Wnm = Wsm + TILE_F;
    const int row0 = blockIdx.x * 64;
    float acc_s[4][4] = {{0.f}};
    float acc_n[4][4] = {{0.f}};

    for (int st = 0; st < 2; ++st) {
        const int kc = grp * 128 + st * 64;
#pragma unroll
        for (int it = 0; it < 4; ++it) {
            int q = t + 256 * it;         // 0..1023
            int row = q >> 4;
            int k4 = (q & 15) * 4;
            float4 xv = make_float4(0.f, 0.f, 0.f, 0.f);
            int gr = row0 + row;
            if (gr < M)
                xv = *reinterpret_cast<const float4*>(&X[(size_t)gr * K + kc + k4]);
            *reinterpret_cast<float4*>(&Xs[row * 68 + k4]) = xv;
            *reinterpret_cast<float4*>(&Wsm[row * 68 + k4]) =
                *reinterpret_cast<const float4*>(&Ws_g[(size_t)(kc + row) * 64 + k4]);
            *reinterpret_cast<float4*>(&Wnm[row * 68 + k4]) =
                *reinterpret_cast<const float4*>(&Wn_g[(size_t)(kc + row) * 64 + k4]);
        }
        __syncthreads();
#pragma unroll 4
        for (int kk = 0; kk < 64; ++kk) {
            float av[4], bs[4], bn[4];
#pragma unroll
            for (int j = 0; j < 4; ++j) av[j] = Xs[(ry * 4 + j) * 68 + kk];
#pragma unroll
            for (int i = 0; i < 4; ++i) {
                bs[i] = Wsm[kk * 68 + cx + 16 * i];
                bn[i] = Wnm[kk * 68 + cx + 16 * i];
            }
#pragma unroll
            for (int j = 0; j < 4; ++j)
#pragma unroll
                for (int i = 0; i < 4; ++i) {
                    acc_s[j][i] += av[j] * bs[i];
                    acc_n[j][i] += av[j] * bn[i];
                }
        }
        __syncthreads();
    }

    // combine: grp1 -> its own (dead) LDS region, stride 33 (bank-free)
    float* flat = smem + 3 * TILE_F;
    if (grp == 1) {
        int o = t * 33;
#pragma unroll
        for (int j = 0; j < 4; ++j)
#pragma unroll
            for (int i = 0; i < 4; ++i) {
                flat[o + j * 4 + i]      = acc_s[j][i];
                flat[o + 16 + j * 4 + i] = acc_n[j][i];
            }
    }
    __syncthreads();
    if (grp == 0) {
        int o = t * 33;
#pragma unroll
        for (int j = 0; j < 4; ++j)
#pragma unroll
            for (int i = 0; i < 4; ++i) {
                acc_s[j][i] += flat[o + j * 4 + i];
                acc_n[j][i] += flat[o + 16 + j * 4 + i];
            }
#pragma unroll
        for (int j = 0; j < 4; ++j) {
            int r = row0 + ry * 4 + j;
            if (r < M) {
#pragma unroll
                for (int i = 0; i < 4; ++i) {
                    int col = cx + 16 * i;
                    S[(size_t)r * DH + col] = acc_s[j][i] + bias[col];
                    P[(size_t)r * DH + col] = f2bf(acc_n[j][i]);
                    Hn_out[(size_t)r * DH + col] = 0.f;
                }
            }
        }
    }
}

// ---- dual GEMM layers 2/3 (K=64): X = relu(S + Hn/deg) fused on load ------
// 512 threads: all stage the single 64x64 tile-set once; grp0 computes
// kk 0-31, grp1 kk 32-63; combine via stride-33 LDS reuse; grp0 epilogue.
__global__ __launch_bounds__(512) void gemm_dual_kernel(
    const float* __restrict__ X, const float* __restrict__ Ws_g,
    const float* __restrict__ Wn_g, const float* __restrict__ bias,
    const float* __restrict__ Hn_in, const int* __restrict__ cnt8,
    float* __restrict__ S, unsigned short* __restrict__ P,
    float* __restrict__ Hn_out, int M) {
    constexpr int K = 64;
    __shared__ float smem[3 * TILE_F];    // Xs, Ws, Wn (combine reuses base)
    int tid = threadIdx.x;
    const int grp = tid >> 8;
    const int t   = tid & 255;
    const int cx = t & 15;
    const int ry = t >> 4;
    float* Xs  = smem;
    float* Wsm = smem + TILE_F;
    float* Wnm = smem + 2 * TILE_F;
    const int row0 = blockIdx.x * 64;
    float acc_s[4][4] = {{0.f}};
    float acc_n[4][4] = {{0.f}};

    {   // stage by all 512 threads (2 passes cover 64 rows x 16 k4-groups)
#pragma unroll
        for (int it = 0; it < 2; ++it) {
            int q = tid + 512 * it;       // 0..1023
            int row = q >> 4;
            int k4 = (q & 15) * 4;
            float4 xv = make_float4(0.f, 0.f, 0.f, 0.f);
            int gr = row0 + row;
            if (gr < M) {
                xv = *reinterpret_cast<const float4*>(&X[(size_t)gr * K + k4]);
                float4 hv = *reinterpret_cast<const float4*>(&Hn_in[(size_t)gr * DH + k4]);
                float inv = 1.f / fmaxf((float)deg8(cnt8, gr), 1.f);
                xv.x = fmaxf(fmaf(hv.x, inv, xv.x), 0.f);
                xv.y = fmaxf(fmaf(hv.y, inv, xv.y), 0.f);
                xv.z = fmaxf(fmaf(hv.z, inv, xv.z), 0.f);
                xv.w = fmaxf(fmaf(hv.w, inv, xv.w), 0.f);
            }
            *reinterpret_cast<float4*>(&Xs[row * 68 + k4]) = xv;
            *reinterpret_cast<float4*>(&Wsm[row * 68 + k4]) =
                *reinterpret_cast<const float4*>(&Ws_g[(size_t)row * 64 + k4]);
            *reinterpret_cast<float4*>(&Wnm[row * 68 + k4]) =
                *reinterpret_cast<const float4*>(&Wn_g[(size_t)row * 64 + k4]);
        }
        __syncthreads();
        const int kk0 = grp * 32;
#pragma unroll 4
        for (int kk = kk0; kk < kk0 + 32; ++kk) {
            float av[4], bs[4], bn[4];
#pragma unroll
            for (int j = 0; j < 4; ++j) av[j] = Xs[(ry * 4 + j) * 68 + kk];
#pragma unroll
            for (int i = 0; i < 4; ++i) {
                bs[i] = Wsm[kk * 68 + cx + 16 * i];
                bn[i] = Wnm[kk * 68 + cx + 16 * i];
            }
#pragma unroll
            for (int j = 0; j < 4; ++j)
#pragma unroll
                for (int i = 0; i < 4; ++i) {
                    acc_s[j][i] += av[j] * bs[i];
                    acc_n[j][i] += av[j] * bn[i];
                }
        }
        __syncthreads();   // all reads of Xs/Ws/Wn done -> safe to reuse
    }

    // combine: grp1 partials into reused smem base, stride 33
    if (grp == 1) {
        int o = t * 33;
#pragma unroll
        for (int j = 0; j < 4; ++j)
#pragma unroll
            for (int i = 0; i < 4; ++i) {
                smem[o + j * 4 + i]      = acc_s[j][i];
                smem[o + 16 + j * 4 + i] = acc_n[j][i];
            }
    }
    __syncthreads();
    if (grp == 0) {
        int o = t * 33;
#pragma unroll
        for (int j = 0; j < 4; ++j)
#pragma unroll
            for (int i = 0; i < 4; ++i) {
                acc_s[j][i] += smem[o + j * 4 + i];
                acc_n[j][i] += smem[o + 16 + j * 4 + i];
            }
#pragma unroll
        for (int j = 0; j < 4; ++j) {
            int r = row0 + ry * 4 + j;
            if (r < M) {
#pragma unroll
                for (int i = 0; i < 4; ++i) {
                    int col = cx + 16 * i;
                    S[(size_t)r * DH + col] = acc_s[j][i] + bias[col];
                    P[(size_t)r * DH + col] = f2bf(acc_n[j][i]);
                    Hn_out[(size_t)r * DH + col] = 0.f;
                }
            }
        }
    }
}

// ---- aggregation: src-bucket LDS slice, wave-per-(dst,bucket) row ----------
// grid = NSB * DTILES blocks x 1024 threads. LDS = 1250*64 bf16 = 160,000 B.
__global__ __launch_bounds__(1024) void agg_kernel(
    const unsigned short* __restrict__ P, const int* __restrict__ cnt8,
    const int* __restrict__ es, float* __restrict__ Hn, int M, int npb8) {
    __shared__ __align__(16) unsigned short sP[MAXNPB * DH];
    int tid = threadIdx.x;
    int sb    = blockIdx.x & (NSB - 1);
    int dtile = blockIdx.x >> 3;
    int s0 = sb * npb8;
    int snodes = min(npb8, M - s0);

    // stage this bucket's P slice (coalesced uint4)
    {
        const uint4* gp = reinterpret_cast<const uint4*>(P + (size_t)s0 * DH);
        int cnt = snodes * 8;   // 128 B/node / 16 B
        for (int j = tid; j < cnt; j += 1024)
            *reinterpret_cast<uint4*>(&sP[j * 8]) = gp[j];
    }
    __syncthreads();

    int lane = tid & 63, wid = tid >> 6;
    int dpb  = (M + DTILES - 1) / DTILES;
    int d0t  = dtile * dpb;
    int dend = min(d0t + dpb, M);

    for (int dstn = d0t + wid; dstn < dend; dstn += 16) {
        int key = dstn * NSB + sb;
        int cnt = min(cnt8[key], CAP);
        if (cnt == 0) continue;
        size_t base = (size_t)key * CAP;
        float acc = 0.f;
        int cmax = cnt - 1;
        for (int e = 0; e < cnt; e += 4) {
            int i0 = es[base + min(e + 0, cmax)] - s0;
            int i1 = es[base + min(e + 1, cmax)] - s0;
            int i2 = es[base + min(e + 2, cmax)] - s0;
            int i3 = es[base + min(e + 3, cmax)] - s0;
            float m1 = (e + 1 < cnt) ? 1.f : 0.f;
            float m2 = (e + 2 < cnt) ? 1.f : 0.f;
            float m3 = (e + 3 < cnt) ? 1.f : 0.f;
            float f0 = bfu(sP[(size_t)i0 * DH + lane]);
            float f1 = bfu(sP[(size_t)i1 * DH + lane]);
            float f2 = bfu(sP[(size_t)i2 * DH + lane]);
            float f3 = bfu(sP[(size_t)i3 * DH + lane]);
            acc += f0;                       // e+0 always valid in-loop
            acc = fmaf(m1, f1, acc);
            acc = fmaf(m2, f2, acc);
            acc = fmaf(m3, f3, acc);
        }
        atomicAdd(&Hn[(size_t)dstn * DH + lane], acc);   // coalesced 256 B
    }
}

// ---- fused finish + readout (last-block-done ticket) ----------------------
__global__ __launch_bounds__(256) void finish_readout_kernel(
    const float* __restrict__ S, const float* __restrict__ Hn,
    const int* __restrict__ cnt8, const int* __restrict__ graph_id,
    float* __restrict__ H, float* __restrict__ gsum, float* __restrict__ gcnt,
    const float* __restrict__ Wc, const float* __restrict__ bc,
    float* __restrict__ out, float* __restrict__ out_feat,
    unsigned int* __restrict__ done, int M, int fb) {
    int tid  = threadIdx.x;
    int lane = tid & 63;
    int wv   = tid >> 6;
    {   // ---- finish work (R10/R11-proven) ----
        int wid = blockIdx.x * 4 + wv;
        int nw  = fb * 4;
        int cpw = (M + nw - 1) / nw;
        int n0 = wid * cpw, n1 = min(n0 + cpw, M);
        if (n0 < n1) {
            float acc = 0.f;
            int cnt = 0;
            int cur = graph_id[n0];
            for (int n = n0; n < n1; ++n) {
                int gid = graph_id[n];
                if (gid != cur) {
                    atomicAdd(&gsum[cur * DH + lane], acc);
                    if (lane == 0) atomicAdd(&gcnt[cur], (float)cnt);
                    acc = 0.f; cnt = 0; cur = gid;
                }
                float inv = 1.f / fmaxf((float)deg8(cnt8, n), 1.f);
                size_t o = (size_t)n * DH + lane;
                float val = fmaf(Hn[o], inv, S[o]);
                H[o] = val;
                acc += val;
                ++cnt;
            }
            atomicAdd(&gsum[cur * DH + lane], acc);
            if (lane == 0) atomicAdd(&gcnt[cur], (float)cnt);
        }
    }

    // ---- last-block ticket ----
    __shared__ unsigned int s_ticket;
    __syncthreads();
    if (tid == 0) {
        __threadfence();   // release: publish this block's gsum/gcnt/H
        s_ticket = __hip_atomic_fetch_add(done, 1u, __ATOMIC_ACQ_REL,
                                          __HIP_MEMORY_SCOPE_AGENT);
    }
    __syncthreads();
    if (s_ticket != (unsigned int)(fb - 1)) return;
    if (tid == 0) __threadfence();   // acquire: see all blocks' gsum/gcnt
    __syncthreads();

    // ---- readout by the last block (256 threads, 4 entries each) ----
    __shared__ float ofs[NG][DH];
#pragma unroll
    for (int q = 0; q < 4; ++q) {
        int idx = tid + 256 * q;            // 0..1023 = (g,d)
        int g = idx >> 6, d = idx & 63;
        float of = gsum[idx] / fmaxf(gcnt[g], 1.0f);
        out_feat[idx] = of;
        ofs[g][d] = of;
    }
    __syncthreads();
    if (tid < NG * 2) {
        int gg = tid >> 1, cc = tid & 1;
        float accv = bc[cc];
#pragma unroll 8
        for (int dd = 0; dd < DH; ++dd) accv += ofs[gg][dd] * Wc[dd * 2 + cc];
        out[gg * 2 + cc] = accv;
    }
}

extern "C" void kernel_launch(void* const* d_in, const int* in_sizes, int n_in,
                              void* d_out, int out_size, void* d_ws, size_t ws_size,
                              hipStream_t stream) {
    const float* feat     = (const float*)d_in[0];
    const int*   src      = (const int*)d_in[1];
    const int*   dst      = (const int*)d_in[2];
    const int*   graph_id = (const int*)d_in[3];
    const float* Ws1 = (const float*)d_in[4];
    const float* Wn1 = (const float*)d_in[5];
    const float* b1  = (const float*)d_in[6];
    const float* Ws2 = (const float*)d_in[7];
    const float* Wn2 = (const float*)d_in[8];
    const float* b2  = (const float*)d_in[9];
    const float* Ws3 = (const float*)d_in[10];
    const float* Wn3 = (const float*)d_in[11];
    const float* b3  = (const float*)d_in[12];
    const float* Wc  = (const float*)d_in[13];
    const float* bc  = (const float*)d_in[14];

    const int M  = in_sizes[3];     // 10000 nodes
    const int E  = in_sizes[1];     // 320000 edges
    const int M2 = M * NSB;         // 80000 (dst,bucket) rows
    const int npb8 = (M + NSB - 1) / NSB;   // 1250 (<= MAXNPB)

    float* out      = (float*)d_out;             // 16 x 2
    float* out_feat = out + NG * 2;              // 16 x 64
    float* Hbuf     = out_feat + NG * DH;        // 10000 x 64 (final h)

    // workspace layout (256B-aligned carves)
    char* w = (char*)d_ws;
    size_t off = 0;
    auto carve = [&](size_t bytes) {
        size_t o = off;
        off = (off + bytes + 255) & ~(size_t)255;
        return o;
    };
    int*   cnt8  = (int*)  (w + carve((size_t)M2 * 4));
    float* gsum  = (float*)(w + carve((size_t)NG * DH * 4));
    float* gcnt  = (float*)(w + carve((size_t)NG * 4));
    unsigned int* done = (unsigned int*)(w + carve(4));
    size_t zero_bytes = off;                       // cnt8 + gsum + gcnt + done
    int*   es    = (int*)  (w + carve((size_t)M2 * CAP * 4));   // 10.24 MB
    float* Sbuf  = (float*)(w + carve((size_t)M * DH * 4));
    unsigned short* Pbuf = (unsigned short*)(w + carve((size_t)M * DH * 2));
    float* Hn    = (float*)(w + carve((size_t)M * DH * 4));
    (void)ws_size; (void)n_in; (void)out_size;

    (void)hipMemsetAsync(d_ws, 0, zero_bytes, stream);

    int gb = (M + 63) / 64;          // 157 gemm blocks
    int eb = (E + 511) / 512;        // 625 build blocks (512 thr)
    int ab = NSB * DTILES;           // 256 agg blocks (1/CU)
    int fb = 160;                    // finish blocks: 640 waves

    // layer 1 (K=256, split-K) + CSR build, ONE dispatch
    gemm1_build_kernel<<<gb + eb, 512, 0, stream>>>(
        feat, Ws1, Wn1, b1, Sbuf, Pbuf, Hn,
        src, dst, cnt8, es, M, E, npb8, gb);
    agg_kernel<<<ab, 1024, 0, stream>>>(Pbuf, cnt8, es, Hn, M, npb8);

    // layer 2 (K=64, split-kk): X = relu(S1 + Hn1/deg) fused; in-place S/Hn
    // is block-safe (each block reads only its own rows before writing them)
    gemm_dual_kernel<<<gb, 512, 0, stream>>>(
        Sbuf, Ws2, Wn2, b2, Hn, cnt8, Sbuf, Pbuf, Hn, M);
    agg_kernel<<<ab, 1024, 0, stream>>>(Pbuf, cnt8, es, Hn, M, npb8);

    // layer 3 (K=64, split-kk): X = relu(S2 + Hn2/deg) fused
    gemm_dual_kernel<<<gb, 512, 0, stream>>>(
        Sbuf, Ws3, Wn3, b3, Hn, cnt8, Sbuf, Pbuf, Hn, M);
    agg_kernel<<<ab, 1024, 0, stream>>>(Pbuf, cnt8, es, Hn, M, npb8);

    // finish layer 3 + readout (fused via last-block-done ticket)
    finish_readout_kernel<<<fb, 256, 0, stream>>>(
        Sbuf, Hn, cnt8, graph_id, Hbuf, gsum, gcnt,
        Wc, bc, out, out_feat, done, M, fb);
}